// Round 8
// baseline (340.809 us; speedup 1.0000x reference)
//
#include <hip/hip_runtime.h>
#include <hip/hip_fp16.h>

// ImportancePooling: N=100000, K=32, D=64.
// R7 analysis: gather fetch is at the per-XCD COMPULSORY floor (each XCD
// reads ~all of xh once; random-line path pinned at ~3.8 TB/s). Fix: slice
// the feature dim 4-ways (16 feats = 32 B/row) so each XCD's slice footprint
// (3.2 MB) fits its 4 MiB L2 -> gathers become L2 hits. Slice = XCC_ID&3
// (measured hw reg), per-slice atomic work-stealing; blocks help other
// slices when done (stores idempotent -> correct even if XCC_ID misbehaves).

#define K_NBR 32
#define D_FEAT 64
#define CHUNK 128          // nodes per block-grab (4 waves x 32)
#define WS_COUNTER_PAD 256 // bytes reserved at d_ws start for counters

typedef float vfloat4 __attribute__((ext_vector_type(4)));
typedef float vfloat2 __attribute__((ext_vector_type(2)));
typedef unsigned int vuint2 __attribute__((ext_vector_type(2)));

__global__ __launch_bounds__(256) void ImportancePooling_28424093564958_convert(
    const vfloat4* __restrict__ x4, vuint2* __restrict__ xh4,
    unsigned int* __restrict__ counters, int n4) {
  if (blockIdx.x == 0 && threadIdx.x < 8) counters[threadIdx.x] = 0u;
  const int i = blockIdx.x * blockDim.x + threadIdx.x;
  if (i < n4) {
    const vfloat4 v = __builtin_nontemporal_load(x4 + i);  // x read once
    const __half2 a = __floats2half2_rn(v.x, v.y);
    const __half2 b = __floats2half2_rn(v.z, v.w);
    vuint2 u;
    u.x = *(const unsigned int*)&a;
    u.y = *(const unsigned int*)&b;
    xh4[i] = u;
  }
}

__global__ __launch_bounds__(256) void ImportancePooling_28424093564958_kernel(
    const __half* __restrict__ xh,      // [N, 64] staged fp16
    const int* __restrict__ neighbors,  // [N, 32]
    const float* __restrict__ weights,  // [N, 32]
    float* __restrict__ out,            // [N, 64]
    unsigned int* __restrict__ counters,
    int N) {
  int xcc;
  asm volatile("s_getreg_b32 %0, hwreg(HW_REG_XCC_ID)" : "=s"(xcc));
  const int lane = threadIdx.x & 63;
  const int wv = threadIdx.x >> 6;  // wave in block, 0..3
  const int j = lane >> 3;          // node-sub within unit, 0..7
  const int c = lane & 7;           // feature-pair, 0..7
  const int vb = (lane & 0x38) << 2;  // bpermute byte base for group j

  __shared__ unsigned int sbase;

  // Own slice first, then help the other 3 (idempotent stores -> safe).
  for (int s2 = 0; s2 < 4; ++s2) {
    const int slice = (xcc + s2) & 3;
    const char* xh_s = (const char*)xh + (slice << 5);  // +slice*32 B

    for (;;) {
      if (threadIdx.x == 0) sbase = atomicAdd(&counters[slice], (unsigned)CHUNK);
      __syncthreads();
      const unsigned base = sbase;
      __syncthreads();
      if (base >= (unsigned)N) break;

      #pragma unroll
      for (int u = 0; u < 4; ++u) {
        const int n0 = (int)base + wv * 32 + u * 8;  // unit's first node
        const int nj = n0 + j;                        // this lane's node
        const bool valid = nj < N;
        const long hb = (long)(valid ? nj : (N - 1)) * K_NBR;

        // Headers: lane (j,c) holds w/idx [nj][m*8+c] in 4+4 regs (nt).
        float wreg[4];
        int ireg[4];
        #pragma unroll
        for (int m = 0; m < 4; ++m) {
          wreg[m] = __builtin_nontemporal_load(weights + hb + m * 8 + c);
          ireg[m] = __builtin_nontemporal_load(neighbors + hb + m * 8 + c);
        }

        // wsum over the node's 32 weights: 4 regs + xor-reduce over c (1,2,4).
        float ws = (wreg[0] + wreg[1]) + (wreg[2] + wreg[3]);
        ws += __shfl_xor(ws, 1, 64);
        ws += __shfl_xor(ws, 2, 64);
        ws += __shfl_xor(ws, 4, 64);
        const float inv = (ws > 0.0f) ? (1.0f / ws) : 1.0f;

        float ax = 0.0f, ay = 0.0f;
        #pragma unroll
        for (int k = 0; k < K_NBR; ++k) {
          const int m = k >> 3;
          const int off = (k & 7) << 2;
          const int wb = __builtin_amdgcn_ds_bpermute(vb + off, __float_as_int(wreg[m]));
          const int ix = __builtin_amdgcn_ds_bpermute(vb + off, ireg[m]);
          const float wk = __int_as_float(wb);
          // 32 B slice of row ix: group j's 8 lanes read half2 each (L2-hit).
          const __half2 h = *(const __half2*)(xh_s + ((long)(unsigned)ix << 7) + (c << 2));
          ax = fmaf(wk, __low2float(h), ax);
          ay = fmaf(wk, __high2float(h), ay);
        }

        if (valid) {
          vfloat2 o2;
          o2.x = ax * inv;
          o2.y = ay * inv;
          __builtin_nontemporal_store(
              o2, (vfloat2*)(out + (long)nj * D_FEAT + (slice << 4) + (c << 1)));
        }
      }
    }
  }
}

// Fallback (ws too small): direct fp32 gather, identical math.
__global__ __launch_bounds__(256) void ImportancePooling_28424093564958_f32(
    const float* __restrict__ x, const int* __restrict__ neighbors,
    const float* __restrict__ weights, float* __restrict__ out, int N) {
  const int wave_id = (int)((blockIdx.x * blockDim.x + threadIdx.x) >> 6);
  const int lane = threadIdx.x & 63;
  if (wave_id >= N) return;
  const long hbase = (long)wave_id * K_NBR;
  int packed;
  if (lane < K_NBR) {
    packed = __float_as_int(weights[hbase + lane]);
  } else {
    packed = neighbors[hbase + (lane - K_NBR)];
  }
  float acc = 0.0f, wsum = 0.0f;
  #pragma unroll
  for (int k = 0; k < K_NBR; ++k) {
    const float wk = __int_as_float(__builtin_amdgcn_readlane(packed, k));
    const int idx = __builtin_amdgcn_readlane(packed, K_NBR + k);
    wsum += wk;
    acc += wk * x[(long)idx * D_FEAT + lane];
  }
  const float inv = (wsum > 0.0f) ? (1.0f / wsum) : 1.0f;
  out[(long)wave_id * D_FEAT + lane] = acc * inv;
}

extern "C" void kernel_launch(void* const* d_in, const int* in_sizes, int n_in,
                              void* d_out, int out_size, void* d_ws, size_t ws_size,
                              hipStream_t stream) {
  const float* x = (const float*)d_in[0];
  const int* neighbors = (const int*)d_in[1];
  const float* weights = (const float*)d_in[2];
  float* out = (float*)d_out;

  const int N = in_sizes[0] / D_FEAT;  // 100000
  const size_t xh_bytes = (size_t)N * D_FEAT * sizeof(__half);

  if (ws_size >= xh_bytes + WS_COUNTER_PAD) {
    unsigned int* counters = (unsigned int*)d_ws;
    __half* xh = (__half*)((char*)d_ws + WS_COUNTER_PAD);

    const int n4 = N * D_FEAT / 4;
    ImportancePooling_28424093564958_convert<<<(n4 + 255) / 256, 256, 0, stream>>>(
        (const vfloat4*)x, (vuint2*)xh, counters, n4);

    // Persistent-ish grid: 8 blocks/CU x 256 CUs; work-stealing balances.
    ImportancePooling_28424093564958_kernel<<<2048, 256, 0, stream>>>(
        xh, neighbors, weights, out, counters, N);
  } else {
    const int block = 256;
    const int grid = (N * 64 + block - 1) / block;
    ImportancePooling_28424093564958_f32<<<grid, block, 0, stream>>>(
        x, neighbors, weights, out, N);
  }
}

// Round 9
// 269.064 us; speedup vs baseline: 1.2666x; 1.2666x over previous
//
#include <hip/hip_runtime.h>
#include <hip/hip_fp16.h>

// ImportancePooling: N=100000, K=32, D=64.
// R8 failed because feature-slicing was WITHIN the 128B cache line (slice
// line-footprint stayed 12.8MB). Fix: slice-major staging layout
// xh[s][n][16 halfs] -> slice s is a contiguous 3.2MB block that fits a
// 4MiB per-XCD L2. Gathers become L2 hits; HBM traffic is the sequential
// header stream (4x) + compulsory slice fill. Slice pinned by HW_REG_XCC_ID
// (&3); work-steal counters + help-other-slices keep it correct regardless
// of dispatch mapping (stores idempotent).

#define K_NBR 32
#define D_FEAT 64
#define CHUNK 128           // nodes per block-grab (4 waves x 32)
#define WS_COUNTER_PAD 256  // bytes reserved at d_ws start for counters

typedef float vfloat2 __attribute__((ext_vector_type(2)));

__global__ __launch_bounds__(256) void ImportancePooling_28424093564958_convert(
    const vfloat2* __restrict__ x2,   // [N*32] float2 view of x
    __half2* __restrict__ xh2,        // [4][N*8] slice-major half2
    unsigned int* __restrict__ counters, int N8) {  // N8 = N*8
  if (blockIdx.x == 0 && threadIdx.x < 8) counters[threadIdx.x] = 0u;
  const int t = blockIdx.x * blockDim.x + threadIdx.x;
  if (t < N8) {
    const int n = t >> 3;   // node
    const int c2 = t & 7;   // half2 col within slice
    #pragma unroll
    for (int s = 0; s < 4; ++s) {
      const vfloat2 v = __builtin_nontemporal_load(x2 + (long)n * 32 + s * 8 + c2);
      xh2[(long)s * N8 + t] = __floats2half2_rn(v.x, v.y);
    }
  }
}

__global__ __launch_bounds__(256) void ImportancePooling_28424093564958_kernel(
    const __half* __restrict__ xh,      // [4][N][16] slice-major fp16
    const int* __restrict__ neighbors,  // [N, 32]
    const float* __restrict__ weights,  // [N, 32]
    float* __restrict__ out,            // [N, 64]
    unsigned int* __restrict__ counters,
    int N) {
  int xcc;
  asm volatile("s_getreg_b32 %0, hwreg(HW_REG_XCC_ID)" : "=s"(xcc));
  const int lane = threadIdx.x & 63;
  const int wv = threadIdx.x >> 6;    // wave in block, 0..3
  const int j = lane >> 3;            // node-sub within octet, 0..7
  const int c = lane & 7;             // half2 col, 0..7
  const int vb = (lane & 0x38) << 2;  // bpermute byte base for group j
  const size_t slice_bytes = (size_t)N * 32;

  __shared__ unsigned int sbase;

  // Own slice first, then help the other 3 (idempotent stores -> safe).
  for (int s2 = 0; s2 < 4; ++s2) {
    const int slice = (xcc + s2) & 3;
    const char* xh_s = (const char*)xh + (size_t)slice * slice_bytes;

    for (;;) {
      if (threadIdx.x == 0) sbase = atomicAdd(&counters[slice], (unsigned)CHUNK);
      __syncthreads();
      const unsigned base = sbase;
      __syncthreads();
      if (base >= (unsigned)N) break;

      #pragma unroll
      for (int u = 0; u < 4; ++u) {
        const int n0 = (int)base + wv * 32 + u * 8;  // octet's first node
        const int nj = n0 + j;                        // this lane's node
        const bool valid = nj < N;
        const long hb = (long)(valid ? nj : (N - 1)) * K_NBR;

        // Headers: lane (j,c) holds w/idx [nj][m*8+c] in 4+4 regs (nt).
        float wreg[4];
        int ireg[4];
        #pragma unroll
        for (int m = 0; m < 4; ++m) {
          wreg[m] = __builtin_nontemporal_load(weights + hb + m * 8 + c);
          ireg[m] = __builtin_nontemporal_load(neighbors + hb + m * 8 + c);
        }

        // wsum over the node's 32 weights: 4 regs + xor-reduce over c (1,2,4).
        float ws = (wreg[0] + wreg[1]) + (wreg[2] + wreg[3]);
        ws += __shfl_xor(ws, 1, 64);
        ws += __shfl_xor(ws, 2, 64);
        ws += __shfl_xor(ws, 4, 64);
        const float inv = (ws > 0.0f) ? (1.0f / ws) : 1.0f;

        float ax = 0.0f, ay = 0.0f;
        #pragma unroll
        for (int k = 0; k < K_NBR; ++k) {
          const int m = k >> 3;
          const int off = (k & 7) << 2;
          const int wb = __builtin_amdgcn_ds_bpermute(vb + off, __float_as_int(wreg[m]));
          const int ix = __builtin_amdgcn_ds_bpermute(vb + off, ireg[m]);
          const float wk = __int_as_float(wb);
          // 32B slice row of node ix (contiguous, L2-resident).
          const __half2 h =
              *(const __half2*)(xh_s + (size_t)(unsigned)ix * 32 + (c << 2));
          ax = fmaf(wk, __low2float(h), ax);
          ay = fmaf(wk, __high2float(h), ay);
        }

        if (valid) {
          vfloat2 o2;
          o2.x = ax * inv;
          o2.y = ay * inv;
          __builtin_nontemporal_store(
              o2, (vfloat2*)(out + (long)nj * D_FEAT + (slice << 4) + (c << 1)));
        }
      }
    }
  }
}

// Fallback (ws too small): direct fp32 gather, identical math.
__global__ __launch_bounds__(256) void ImportancePooling_28424093564958_f32(
    const float* __restrict__ x, const int* __restrict__ neighbors,
    const float* __restrict__ weights, float* __restrict__ out, int N) {
  const int wave_id = (int)((blockIdx.x * blockDim.x + threadIdx.x) >> 6);
  const int lane = threadIdx.x & 63;
  if (wave_id >= N) return;
  const long hbase = (long)wave_id * K_NBR;
  int packed;
  if (lane < K_NBR) {
    packed = __float_as_int(weights[hbase + lane]);
  } else {
    packed = neighbors[hbase + (lane - K_NBR)];
  }
  float acc = 0.0f, wsum = 0.0f;
  #pragma unroll
  for (int k = 0; k < K_NBR; ++k) {
    const float wk = __int_as_float(__builtin_amdgcn_readlane(packed, k));
    const int idx = __builtin_amdgcn_readlane(packed, K_NBR + k);
    wsum += wk;
    acc += wk * x[(long)idx * D_FEAT + lane];
  }
  const float inv = (wsum > 0.0f) ? (1.0f / wsum) : 1.0f;
  out[(long)wave_id * D_FEAT + lane] = acc * inv;
}

extern "C" void kernel_launch(void* const* d_in, const int* in_sizes, int n_in,
                              void* d_out, int out_size, void* d_ws, size_t ws_size,
                              hipStream_t stream) {
  const float* x = (const float*)d_in[0];
  const int* neighbors = (const int*)d_in[1];
  const float* weights = (const float*)d_in[2];
  float* out = (float*)d_out;

  const int N = in_sizes[0] / D_FEAT;  // 100000
  const size_t xh_bytes = (size_t)N * D_FEAT * sizeof(__half);

  if (ws_size >= xh_bytes + WS_COUNTER_PAD) {
    unsigned int* counters = (unsigned int*)d_ws;
    __half* xh = (__half*)((char*)d_ws + WS_COUNTER_PAD);

    const int N8 = N * 8;
    ImportancePooling_28424093564958_convert<<<(N8 + 255) / 256, 256, 0, stream>>>(
        (const vfloat2*)x, (__half2*)xh, counters, N8);

    ImportancePooling_28424093564958_kernel<<<2048, 256, 0, stream>>>(
        xh, neighbors, weights, out, counters, N);
  } else {
    const int block = 256;
    const int grid = (N * 64 + block - 1) / block;
    ImportancePooling_28424093564958_f32<<<grid, block, 0, stream>>>(
        x, neighbors, weights, out, N);
  }
}